// Round 5
// baseline (169.757 us; speedup 1.0000x reference)
//
#include <hip/hip_runtime.h>
#include <hip/hip_bf16.h>
#include <math.h>

#define N_NODES 10000
#define N_EDGES 640000
#define N_GRAPHS 64
#define DIM 128
#define NEG_SLOPE 0.01f
#define NB_CSR 128            // histogram partitions (5000 edges each)
#define EDGES_PER_BLK (N_EDGES / NB_CSR)

typedef __attribute__((ext_vector_type(8))) short bf16x8;
typedef __attribute__((ext_vector_type(4))) float f32x4;

// ---------------- workspace layout (bytes) ----------------
// resid    : 0          .. 10,240,000   float[2][10000][128]
// a_self   : 10,240,000                 float[2][10000]
// a_nb     : 10,320,000                 float[2][10000]
// deg      : 10,400,000                 int[10000]
// rowptr   : 10,440,000                 int[10001]
// csr_src  : 10,480,032                 int[640000]
// feat_b16 : 13,040,032 .. 18,160,032   bf16[2][10000][128]
// bh       : 18,160,032 .. 23,280,032   int[128][10000]

__device__ __forceinline__ unsigned short f2bf(float f) {
    __hip_bfloat16 h = __float2bfloat16(f);
    return *reinterpret_cast<unsigned short*>(&h);
}

// ---------------- CSR build: phase 1, per-partition LDS histogram ----------------
__global__ __launch_bounds__(1024) void csr_hist(const int4* __restrict__ edst4,
                                                 int* __restrict__ bh) {
    __shared__ int hist[N_NODES];
    const int blk = blockIdx.x;
    const int t = threadIdx.x;
    for (int n = t; n < N_NODES; n += 1024) hist[n] = 0;
    __syncthreads();
    const int base4 = blk * (EDGES_PER_BLK / 4);
    for (int i = t; i < EDGES_PER_BLK / 4; i += 1024) {
        int4 d = edst4[base4 + i];
        atomicAdd(&hist[d.x], 1);
        atomicAdd(&hist[d.y], 1);
        atomicAdd(&hist[d.z], 1);
        atomicAdd(&hist[d.w], 1);
    }
    __syncthreads();
    int* dst = bh + (size_t)blk * N_NODES;
    for (int n = t; n < N_NODES; n += 1024) dst[n] = hist[n];
}

// ---------------- CSR build: phase 2, per-node scan over partitions (int4) ----------------
__global__ __launch_bounds__(256) void csr_node_scan(int* __restrict__ bh,
                                                     int* __restrict__ deg) {
    int n4 = blockIdx.x * 256 + threadIdx.x;           // group of 4 nodes
    if (n4 >= N_NODES / 4) return;
    int4 run = {0, 0, 0, 0};
    for (int blk = 0; blk < NB_CSR; ++blk) {
        int4* p = reinterpret_cast<int4*>(bh + (size_t)blk * N_NODES) + n4;
        int4 v = *p;
        *p = run;
        run.x += v.x; run.y += v.y; run.z += v.z; run.w += v.w;
    }
    reinterpret_cast<int4*>(deg)[n4] = run;
}

// ---------------- CSR build: phase 3, rowptr scan (+ zero phis) ----------------
__global__ __launch_bounds__(1024) void scan_deg(const int* __restrict__ deg,
                                                 int* __restrict__ rowptr,
                                                 float* __restrict__ phis) {
    __shared__ int sdata[1024];
    const int tid = threadIdx.x;
    // fold in: zero phis (64*256 = 16384 floats)
    for (int i = tid; i < N_GRAPHS * 2 * DIM; i += 1024) phis[i] = 0.f;

    const int base = tid * 10;
    int cnt = N_NODES - base;
    if (cnt < 0) cnt = 0;
    if (cnt > 10) cnt = 10;
    int local[10];
    int s = 0;
    for (int i = 0; i < cnt; ++i) { local[i] = s; s += deg[base + i]; }
    sdata[tid] = s;
    __syncthreads();
    for (int off = 1; off < 1024; off <<= 1) {
        int v = 0;
        if (tid >= off) v = sdata[tid - off];
        __syncthreads();
        if (tid >= off) sdata[tid] += v;
        __syncthreads();
    }
    int pre = (tid == 0) ? 0 : sdata[tid - 1];
    for (int i = 0; i < cnt; ++i) rowptr[base + i] = pre + local[i];
    if (tid == 1023) rowptr[N_NODES] = sdata[1023];
}

// ---------------- CSR build: phase 4, scatter via LDS cursors ----------------
__global__ __launch_bounds__(1024) void csr_scatter(
    const int4* __restrict__ esrc4, const int4* __restrict__ edst4,
    const int* __restrict__ rowptr, const int* __restrict__ bh,
    int* __restrict__ csr_src) {
    __shared__ int cur[N_NODES];
    const int blk = blockIdx.x;
    const int t = threadIdx.x;
    const int* boff = bh + (size_t)blk * N_NODES;
    for (int n = t; n < N_NODES; n += 1024) cur[n] = rowptr[n] + boff[n];
    __syncthreads();
    const int base4 = blk * (EDGES_PER_BLK / 4);
    for (int i = t; i < EDGES_PER_BLK / 4; i += 1024) {
        int4 s = esrc4[base4 + i];
        int4 d = edst4[base4 + i];
        csr_src[atomicAdd(&cur[d.x], 1)] = s.x;
        csr_src[atomicAdd(&cur[d.y], 1)] = s.y;
        csr_src[atomicAdd(&cur[d.z], 1)] = s.z;
        csr_src[atomicAdd(&cur[d.w], 1)] = s.w;
    }
}

// ---------------- MFMA GEMM: 64 nodes x 128 cols, K=128, bf16 ----------------
// grid (ceil(N/64), 4), block 256. y: bit0 = which (0=feat,1=resid), bit1 = b.
// which==0: writes feat_b16 + a_self/a_nb (direct, full j covered per block).
// which==1: writes resid fp32.
__global__ __launch_bounds__(256) void gemm_mfma(
    const float* __restrict__ x, const float* __restrict__ Wfc,
    const float* __restrict__ bfc, const float* __restrict__ Wres,
    const float* __restrict__ wl, const float* __restrict__ wr,
    float* __restrict__ resid, unsigned short* __restrict__ feat_b16,
    float* __restrict__ a_self, float* __restrict__ a_nb) {
    const int which = blockIdx.y & 1;
    const int b = blockIdx.y >> 1;
    const float* __restrict__ W = (which ? Wres : Wfc) + b * DIM * DIM;
    const int n0 = blockIdx.x * 64;
    const int t = threadIdx.x;

    __shared__ unsigned short xs[64][136];   // pad 136: bank-conflict-free frags
    __shared__ unsigned short wsh[128][136];

    // stage x tile -> bf16 LDS (4 threads/row, 32 cols each)
    {
        const int r = t >> 2, qq = t & 3;
        const int n = n0 + r;
        ushort4* drow = reinterpret_cast<ushort4*>(&xs[r][qq * 32]);
        if (n < N_NODES) {
            const float4* p = reinterpret_cast<const float4*>(x + (size_t)n * DIM + qq * 32);
#pragma unroll
            for (int i = 0; i < 8; ++i) {
                float4 v = p[i];
                ushort4 u;
                u.x = f2bf(v.x); u.y = f2bf(v.y); u.z = f2bf(v.z); u.w = f2bf(v.w);
                drow[i] = u;
            }
        } else {
            ushort4 z = {0, 0, 0, 0};
#pragma unroll
            for (int i = 0; i < 8; ++i) drow[i] = z;
        }
    }
    // stage W -> bf16 LDS (2 threads/row, 64 cols each)
    {
        const int rw = t >> 1, hh = t & 1;
        const float4* p = reinterpret_cast<const float4*>(W + (size_t)rw * DIM + hh * 64);
        ushort4* drow = reinterpret_cast<ushort4*>(&wsh[rw][hh * 64]);
#pragma unroll
        for (int i = 0; i < 16; ++i) {
            float4 v = p[i];
            ushort4 u;
            u.x = f2bf(v.x); u.y = f2bf(v.y); u.z = f2bf(v.z); u.w = f2bf(v.w);
            drow[i] = u;
        }
    }
    __syncthreads();

    const int wave = t >> 6, lane = t & 63;
    const int quad = lane >> 4, jc = lane & 15;
    const int m0 = wave * 16;

    // A fragments: lane holds A[m=jc][k=quad*8 + 0..7] for each 32-k step
    bf16x8 af[4];
#pragma unroll
    for (int ks = 0; ks < 4; ++ks)
        af[ks] = *reinterpret_cast<const bf16x8*>(&xs[m0 + jc][ks * 32 + quad * 8]);

    f32x4 accs[8];
    float ps[4] = {0.f, 0.f, 0.f, 0.f}, pr[4] = {0.f, 0.f, 0.f, 0.f};
#pragma unroll
    for (int jt = 0; jt < 8; ++jt) {
        f32x4 acc = {0.f, 0.f, 0.f, 0.f};
#pragma unroll
        for (int ks = 0; ks < 4; ++ks) {
            bf16x8 bfr = *reinterpret_cast<const bf16x8*>(
                &wsh[jt * 16 + jc][ks * 32 + quad * 8]);
            acc = __builtin_amdgcn_mfma_f32_16x16x32_bf16(af[ks], bfr, acc, 0, 0, 0);
        }
        if (!which) {
            float bias = bfc[b * DIM + jt * 16 + jc];
            acc[0] += bias; acc[1] += bias; acc[2] += bias; acc[3] += bias;
            float wlv = wl[b * DIM + jt * 16 + jc];
            float wrv = wr[b * DIM + jt * 16 + jc];
#pragma unroll
            for (int r2 = 0; r2 < 4; ++r2) { ps[r2] += acc[r2] * wlv; pr[r2] += acc[r2] * wrv; }
        }
        accs[jt] = acc;
    }

    __syncthreads();  // all waves done reading xs/wsh

    if (!which) {
        // a_self/a_nb: reduce over the 16 j-lanes (full 128 cols in this block)
#pragma unroll
        for (int off = 8; off > 0; off >>= 1) {
#pragma unroll
            for (int r2 = 0; r2 < 4; ++r2) {
                ps[r2] += __shfl_xor(ps[r2], off, 64);
                pr[r2] += __shfl_xor(pr[r2], off, 64);
            }
        }
        if (jc == 0) {
#pragma unroll
            for (int r2 = 0; r2 < 4; ++r2) {
                int n = n0 + m0 + quad * 4 + r2;
                if (n < N_NODES) {
                    a_self[b * N_NODES + n] = ps[r2];
                    a_nb[b * N_NODES + n] = pr[r2];
                }
            }
        }
        // stage bf16 output into xs, then coalesced store
#pragma unroll
        for (int jt = 0; jt < 8; ++jt)
#pragma unroll
            for (int r2 = 0; r2 < 4; ++r2)
                xs[m0 + quad * 4 + r2][jt * 16 + jc] = f2bf(accs[jt][r2]);
        __syncthreads();
        const int r = t >> 2, qq = t & 3;
        const int n = n0 + r;
        if (n < N_NODES) {
            uint4* dst = reinterpret_cast<uint4*>(
                feat_b16 + ((size_t)b * N_NODES + n) * DIM + qq * 32);
            const uint4* srcp = reinterpret_cast<const uint4*>(&xs[r][qq * 32]);
#pragma unroll
            for (int i = 0; i < 4; ++i) dst[i] = srcp[i];
        }
    } else {
        float* fs = reinterpret_cast<float*>(wsh);  // [64][136] floats (34816 B fits)
#pragma unroll
        for (int jt = 0; jt < 8; ++jt)
#pragma unroll
            for (int r2 = 0; r2 < 4; ++r2)
                fs[(m0 + quad * 4 + r2) * 136 + jt * 16 + jc] = accs[jt][r2];
        __syncthreads();
        const int r = t >> 2, qq = t & 3;
        const int n = n0 + r;
        if (n < N_NODES) {
            float4* dst = reinterpret_cast<float4*>(
                resid + ((size_t)b * N_NODES + n) * DIM + qq * 32);
            const float4* srcp = reinterpret_cast<const float4*>(&fs[r * 136 + qq * 32]);
#pragma unroll
            for (int i = 0; i < 8; ++i) dst[i] = srcp[i];
        }
    }
}

// ---------------- softmax + weighted aggregation + residual + relu ----------------
// grid (2500, 2), block 256 = 4 waves, one node per wave. Single pass (scores
// |s| < ~20 << 88 -> exp(s) safe in fp32; softmax shift-invariant).
__global__ __launch_bounds__(256) void aggregate(
    const unsigned short* __restrict__ feat_b16, const float* __restrict__ resid,
    const float* __restrict__ a_self, const float* __restrict__ a_nb,
    const int* __restrict__ rowptr, const int* __restrict__ csr_src,
    float* __restrict__ out) {
    const int wave = threadIdx.x >> 6;
    const int lane = threadIdx.x & 63;
    const int n = blockIdx.x * 4 + wave;
    const int b = blockIdx.y;
    const int q = lane >> 4;     // edge slot within group of 4
    const int l16 = lane & 15;   // covers channels [l16*8, l16*8+8)
    const int start = rowptr[n];
    const int end = rowptr[n + 1];

    const float* __restrict__ anb = a_nb + b * N_NODES;
    const uint4* __restrict__ fb =
        reinterpret_cast<const uint4*>(feat_b16 + (size_t)b * N_NODES * DIM);
    const float asl = a_self[b * N_NODES + n];

    float acc[8];
#pragma unroll
    for (int k = 0; k < 8; ++k) acc[k] = 0.f;
    float dpart = 0.f;

    for (int c = start; c < end; c += 64) {
        int j = c + lane;
        float e = 0.f;
        int src = 0;
        if (j < end) {
            src = csr_src[j];
            float s = asl + anb[src];
            s = (s >= 0.f) ? s : NEG_SLOPE * s;
            e = __expf(s);
        }
        dpart += e;
        int cnt = end - c;
        if (cnt > 64) cnt = 64;
        int iters = (cnt + 3) >> 2;

        float w0 = __shfl(e, q, 64);
        int s0 = __shfl(src, q, 64);
        uint4 f0 = fb[(size_t)s0 * 16 + l16];

        for (int i2 = 0; i2 < iters - 1; ++i2) {
            int idx = (i2 + 1) * 4 + q;
            float w1 = __shfl(e, idx, 64);
            int s1 = __shfl(src, idx, 64);
            uint4 f1 = fb[(size_t)s1 * 16 + l16];
#pragma unroll
            for (int k = 0; k < 4; ++k) {
                unsigned int u = (&f0.x)[k];
                float lo = __uint_as_float(u << 16);
                float hi = __uint_as_float(u & 0xffff0000u);
                acc[2 * k]     += w0 * lo;
                acc[2 * k + 1] += w0 * hi;
            }
            w0 = w1; f0 = f1;
        }
#pragma unroll
        for (int k = 0; k < 4; ++k) {
            unsigned int u = (&f0.x)[k];
            float lo = __uint_as_float(u << 16);
            float hi = __uint_as_float(u & 0xffff0000u);
            acc[2 * k]     += w0 * lo;
            acc[2 * k + 1] += w0 * hi;
        }
    }

#pragma unroll
    for (int k = 0; k < 8; ++k) {
        acc[k] += __shfl_xor(acc[k], 16, 64);
        acc[k] += __shfl_xor(acc[k], 32, 64);
    }
    float denom = dpart;
#pragma unroll
    for (int off = 32; off > 0; off >>= 1) denom += __shfl_xor(denom, off, 64);

    if (q == 0) {
        float inv = (end > start) ? 1.f / denom : 0.f;
        const float4* rr = reinterpret_cast<const float4*>(
            resid + ((size_t)b * N_NODES + n) * DIM);
        float4 r0 = rr[l16 * 2];
        float4 r1 = rr[l16 * 2 + 1];
        float4 o0, o1;
        o0.x = fmaxf(acc[0] * inv + r0.x, 0.f);
        o0.y = fmaxf(acc[1] * inv + r0.y, 0.f);
        o0.z = fmaxf(acc[2] * inv + r0.z, 0.f);
        o0.w = fmaxf(acc[3] * inv + r0.w, 0.f);
        o1.x = fmaxf(acc[4] * inv + r1.x, 0.f);
        o1.y = fmaxf(acc[5] * inv + r1.y, 0.f);
        o1.z = fmaxf(acc[6] * inv + r1.z, 0.f);
        o1.w = fmaxf(acc[7] * inv + r1.w, 0.f);
        float4* po = reinterpret_cast<float4*>(out + (size_t)n * (2 * DIM) + b * DIM);
        po[l16 * 2] = o0;
        po[l16 * 2 + 1] = o1;
    }
}

// ---------------- per-graph sum pooling ----------------
__device__ int lower_bound_dev(const int* __restrict__ a, int n, int key) {
    int lo = 0, hi = n;
    while (lo < hi) {
        int mid = (lo + hi) >> 1;
        if (a[mid] < key) lo = mid + 1;
        else hi = mid;
    }
    return lo;
}

__global__ __launch_bounds__(256) void pool_graphs(
    const float* __restrict__ h, const int* __restrict__ gids,
    float* __restrict__ phis) {
    const int g = blockIdx.x;
    const int chunk = blockIdx.y;
    const int tid = threadIdx.x;
    int lo = lower_bound_dev(gids, N_NODES, g);
    int hi = lower_bound_dev(gids, N_NODES, g + 1);
    float acc = 0.f;
    for (int n = lo + chunk; n < hi; n += 16) acc += h[(size_t)n * (2 * DIM) + tid];
    if (acc != 0.f) atomicAdd(&phis[(size_t)g * (2 * DIM) + tid], acc);
}

extern "C" void kernel_launch(void* const* d_in, const int* in_sizes, int n_in,
                              void* d_out, int out_size, void* d_ws, size_t ws_size,
                              hipStream_t stream) {
    const float* x    = (const float*)d_in[0];
    const int* esrc   = (const int*)d_in[1];
    const int* edst   = (const int*)d_in[2];
    const int* gids   = (const int*)d_in[3];
    const float* Wfc  = (const float*)d_in[4];
    const float* bfc  = (const float*)d_in[5];
    const float* wl   = (const float*)d_in[6];
    const float* wr   = (const float*)d_in[7];
    const float* Wres = (const float*)d_in[8];
    float* out = (float*)d_out;

    char* ws = (char*)d_ws;
    float* resid   = (float*)(ws + 0);
    float* a_self  = (float*)(ws + 10240000);
    float* a_nb    = (float*)(ws + 10320000);
    int*   deg     = (int*)(ws + 10400000);
    int*   rowptr  = (int*)(ws + 10440000);
    int*   csr_src = (int*)(ws + 10480032);
    unsigned short* feat_b16 = (unsigned short*)(ws + 13040032);
    int*   bh      = (int*)(ws + 18160032);

    float* phis = out + (size_t)N_NODES * 2 * DIM;

    csr_hist<<<NB_CSR, 1024, 0, stream>>>((const int4*)edst, bh);
    csr_node_scan<<<(N_NODES / 4 + 255) / 256, 256, 0, stream>>>(bh, deg);
    scan_deg<<<1, 1024, 0, stream>>>(deg, rowptr, phis);
    csr_scatter<<<NB_CSR, 1024, 0, stream>>>(
        (const int4*)esrc, (const int4*)edst, rowptr, bh, csr_src);

    gemm_mfma<<<dim3((N_NODES + 63) / 64, 4), 256, 0, stream>>>(
        x, Wfc, bfc, Wres, wl, wr, resid, feat_b16, a_self, a_nb);
    aggregate<<<dim3(2500, 2), 256, 0, stream>>>(
        feat_b16, resid, a_self, a_nb, rowptr, csr_src, out);
    pool_graphs<<<dim3(N_GRAPHS, 16), 256, 0, stream>>>(out, gids, phis);
}